// Round 6
// baseline (258.217 us; speedup 1.0000x reference)
//
#include <hip/hip_runtime.h>
#include <hip/hip_bf16.h>

#define B_ 2
#define S_ 2048
#define D_ 1024
#define H_ 16
#define DK_ 64
#define BS_ (B_ * S_)   // 4096

typedef unsigned int u32;
typedef unsigned short u16;
typedef __attribute__((ext_vector_type(8))) short bf16x8;
typedef __attribute__((ext_vector_type(4))) float f32x4;

typedef const __attribute__((address_space(1))) void glb_cv;
typedef __attribute__((address_space(3))) void lds_v;

__device__ __forceinline__ void async_cp16(const void* g, void* l) {
    __builtin_amdgcn_global_load_lds((glb_cv*)g, (lds_v*)l, 16, 0, 0);
}

__device__ __forceinline__ float bf2f(u16 v) {
    union { u32 u; float f; } c; c.u = ((u32)v) << 16; return c.f;
}
__device__ __forceinline__ u16 f2bf(float f) {   // RNE
    union { float f; u32 u; } c; c.f = f;
    u32 u = c.u;
    return (u16)((u + 0x7fffu + ((u >> 16) & 1u)) >> 16);
}
__device__ __forceinline__ u32 pack2(float a, float b) {
    return (u32)f2bf(a) | ((u32)f2bf(b) << 16);
}
// truncating pack (hot attn path only)
__device__ __forceinline__ u32 packtr(float lo, float hi) {
    union { float f; u32 u; } a, b; a.f = lo; b.f = hi;
    return __builtin_amdgcn_perm(b.u, a.u, 0x07060302u);
}
// LDS swizzle for attn tiles
__device__ __forceinline__ int sw64(int r, int c8) { return (((c8) + (r)) & 7) * 8; }

// ------------- fused prep: weight transposes + X f32->bf16 ------------------
// blocks [0,1024): weight transpose (z = id>>8); blocks [1024,7168): X convert.
struct PrepArgs {
    const float* W[4]; u16* WT[4];
    const float* X[3]; u16* XB[3];
};
__global__ __launch_bounds__(256) void prep(PrepArgs a)
{
    const int id = blockIdx.x;
    const int tid = threadIdx.x;
    if (id >= 1024) {   // ---- X convert: 2048 elems/block ----
        const int cid = id - 1024;
        const int z = cid >> 11;
        const size_t base = (size_t)(cid & 2047) * 2048 + tid * 8;
        const float* X = a.X[z];
        float4 x0 = *(const float4*)(X + base);
        float4 x1 = *(const float4*)(X + base + 4);
        uint4 o;
        o.x = pack2(x0.x, x0.y); o.y = pack2(x0.z, x0.w);
        o.z = pack2(x1.x, x1.y); o.w = pack2(x1.z, x1.w);
        *(uint4*)(a.XB[z] + base) = o;
        return;
    }
    __shared__ __attribute__((aligned(16))) u16 T[64][72];
    const int z = id >> 8;
    const int rem = id & 255;
    const float* W = a.W[z];
    u16* WT = a.WT[z];
    const int headMode = (z < 3) ? 1 : 0;
    const int k0 = (rem >> 4) * 64;
    const int n0 = (rem & 15) * 64;
    const int kr = tid >> 4;
    const int n4 = (tid & 15) * 4;
    #pragma unroll
    for (int pass = 0; pass < 4; ++pass) {
        int kk = k0 + pass * 16 + kr;
        const float* p = headMode
            ? (W + (size_t)((n0 + n4) >> 6) * (1024 * 64) + kk * 64 + ((n0 + n4) & 63))
            : (W + (size_t)kk * 1024 + n0 + n4);
        float4 v = *(const float4*)p;
        int krel = pass * 16 + kr;
        T[n4 + 0][krel] = f2bf(v.x);
        T[n4 + 1][krel] = f2bf(v.y);
        T[n4 + 2][krel] = f2bf(v.z);
        T[n4 + 3][krel] = f2bf(v.w);
    }
    __syncthreads();
    const int nr = tid >> 2;
    const int kq = (tid & 3) * 16;
    uint4 o0 = *(const uint4*)&T[nr][kq];
    uint4 o1 = *(const uint4*)&T[nr][kq + 8];
    u16* q = WT + (size_t)(n0 + nr) * 1024 + k0 + kq;
    *(uint4*)q = o0;
    *(uint4*)(q + 8) = o1;
}

// ---------------- fused projections, double-buffered BK=32 -------------------
// Y = XB(bf16) . WT^T + bias; 128x128 tile; stage(k+32) issued BEFORE compute(k)
// so global->LDS loads fly under the MFMAs; ONE barrier per iter (vmcnt drain).
// z==1 negates rows >= 2048 (K batch-1 sign fold).
// z==2 writes DIRECTLY in transposed VT[b][h][dk][t] layout.
struct ProjArgs {
    const u16* X[3];
    const u16* W[3];
    const float* bias[3];
    u16* Y[3];
};
__global__ __launch_bounds__(256) void proj3(ProjArgs pa)
{
    __shared__ __attribute__((aligned(16))) u16 As[2][128][32];
    __shared__ __attribute__((aligned(16))) u16 Bs[2][128][32];
    const int z = blockIdx.z;
    const u16* X = pa.X[z];
    const u16* WT = pa.W[z];
    const float* bias = pa.bias[z];
    u16* Y = pa.Y[z];
    const int neg = (z == 1);

    const int tid = threadIdx.x;
    const int lane = tid & 63;
    const int wave = tid >> 6;
    const int quad = lane >> 4;
    const int l16 = lane & 15;
    const int m0 = blockIdx.x * 128;
    const int n0 = blockIdx.y * 128;
    const int wm = (wave & 1) * 64, wn = (wave >> 1) * 64;

    auto stage = [&](int buf, int k0) {
        #pragma unroll
        for (int call = 0; call < 2; ++call) {
            const int c = tid + call * 256;               // chunk 0..511 (16B each)
            const int row = c >> 2, cc = (c & 3) * 8;     // [row][cc..cc+7]
            char* la = (char*)&As[buf][0][0] + (size_t)(c & ~63) * 16;
            async_cp16(X + (size_t)(m0 + row) * 1024 + k0 + cc, la);
            char* lb = (char*)&Bs[buf][0][0] + (size_t)(c & ~63) * 16;
            async_cp16(WT + (size_t)(n0 + row) * 1024 + k0 + cc, lb);
        }
    };

    f32x4 acc[4][4] = {};

    stage(0, 0);
    __syncthreads();   // drains vmcnt(0): buf0 ready
    int cur = 0;
    for (int k0 = 0; k0 < 1024; k0 += 32) {
        if (k0 + 32 < 1024) stage(cur ^ 1, k0 + 32);   // in flight under MFMA

        bf16x8 af[4], bfr[4];
        #pragma unroll
        for (int mt = 0; mt < 4; ++mt)
            af[mt] = *(const bf16x8*)&As[cur][wm + mt * 16 + l16][quad * 8];
        #pragma unroll
        for (int nt = 0; nt < 4; ++nt)
            bfr[nt] = *(const bf16x8*)&Bs[cur][wn + nt * 16 + l16][quad * 8];
        #pragma unroll
        for (int mt = 0; mt < 4; ++mt)
            #pragma unroll
            for (int nt = 0; nt < 4; ++nt)
                acc[mt][nt] = __builtin_amdgcn_mfma_f32_16x16x32_bf16(
                    af[mt], bfr[nt], acc[mt][nt], 0, 0, 0);

        __syncthreads();   // frag reads done + next-tile loads landed
        cur ^= 1;
    }

    if (z == 2) {
        // transposed V epilogue: VT[((b*16+h)*64+dk)*2048 + t]
        #pragma unroll
        for (int nt = 0; nt < 4; ++nt) {
            const int col = n0 + wn + nt * 16 + l16;
            const float bv = bias[col];
            u16* vrow = Y + ((size_t)(col >> 6) * 64 + (col & 63)) * 2048;
            #pragma unroll
            for (int mt = 0; mt < 4; ++mt) {
                const int row = m0 + wm + mt * 16 + quad * 4;
                const size_t boff = (size_t)(row >> 11) * (16 * 64 * 2048);
                const int t = row & 2047;
                uint2 w;
                w.x = pack2(acc[mt][nt][0] + bv, acc[mt][nt][1] + bv);
                w.y = pack2(acc[mt][nt][2] + bv, acc[mt][nt][3] + bv);
                *(uint2*)(vrow + boff + t) = w;
            }
        }
        return;
    }

    #pragma unroll
    for (int nt = 0; nt < 4; ++nt) {
        const int col = n0 + wn + nt * 16 + l16;
        const float bv = bias[col];
        #pragma unroll
        for (int mt = 0; mt < 4; ++mt) {
            #pragma unroll
            for (int r = 0; r < 4; ++r) {
                const int row = m0 + wm + mt * 16 + quad * 4 + r;
                float v = acc[mt][nt][r] + bv;
                if (neg && row >= 2048) v = -v;
                Y[(size_t)row * 1024 + col] = f2bf(v);
            }
        }
    }
}

// ---------------- output GEMM: d_out = (P0+P1+P2) . WoT^T + bo ---------------
// MFMA linearity (no VALU combine); double-buffered BK=32, stage-before-compute,
// one barrier per iter. hiB rows: out1 = cs.Wo - acc + bo, csRow accumulated
// from the staged Bs tile. 128x64 tile, grid 32x16 = 512 blocks (2/CU).
__global__ __launch_bounds__(256) void gemm_out(
    const u16* __restrict__ P0, const u16* __restrict__ P1,
    const u16* __restrict__ P2, const float* __restrict__ csP,
    const u16* __restrict__ WT, const float* __restrict__ bias,
    float* __restrict__ Y)
{
    __shared__ __attribute__((aligned(16))) u16 Aa[2][128][32];
    __shared__ __attribute__((aligned(16))) u16 Ab[2][128][32];
    __shared__ __attribute__((aligned(16))) u16 Ac[2][128][32];
    __shared__ __attribute__((aligned(16))) u16 Bs[2][64][32];
    __shared__ __attribute__((aligned(16))) float csL[1024];
    __shared__ float csRowL[64];

    const int tid = threadIdx.x;
    const int lane = tid & 63;
    const int wave = tid >> 6;
    const int quad = lane >> 4;
    const int l16 = lane & 15;
    const int m0 = blockIdx.x * 128;
    const int n0 = blockIdx.y * 64;
    const int wm = (wave & 1) * 64, wn = (wave >> 1) * 32;
    const bool hiB = (m0 >= 2048);        // batch-1 rows (block-uniform)

    auto stage = [&](int buf, int k0) {
        #pragma unroll
        for (int call = 0; call < 2; ++call) {
            const int c = tid + call * 256;               // 512 chunks per A tile
            const int row = c >> 2, cc = (c & 3) * 8;
            char* la = (char*)&Aa[buf][0][0] + (size_t)(c & ~63) * 16;
            async_cp16(P0 + (size_t)(m0 + row) * 1024 + k0 + cc, la);
            char* lb = (char*)&Ab[buf][0][0] + (size_t)(c & ~63) * 16;
            async_cp16(P1 + (size_t)(m0 + row) * 1024 + k0 + cc, lb);
            char* lc = (char*)&Ac[buf][0][0] + (size_t)(c & ~63) * 16;
            async_cp16(P2 + (size_t)(m0 + row) * 1024 + k0 + cc, lc);
        }
        {   // B: WoT tile, 256 chunks
            const int c = tid;
            const int row = c >> 2, cc = (c & 3) * 8;
            char* lb = (char*)&Bs[buf][0][0] + (size_t)(c & ~63) * 16;
            async_cp16(WT + (size_t)(n0 + row) * 1024 + k0 + cc, lb);
        }
    };

    // one-time: combined csum vector into LDS (before the initial barrier)
    if (hiB) {
        const int t4 = tid * 4;
        float4 c0 = *(const float4*)(csP + t4);
        float4 c1 = *(const float4*)(csP + 1024 + t4);
        float4 c2 = *(const float4*)(csP + 2048 + t4);
        csL[t4 + 0] = c0.x + c1.x + c2.x;
        csL[t4 + 1] = c0.y + c1.y + c2.y;
        csL[t4 + 2] = c0.z + c1.z + c2.z;
        csL[t4 + 3] = c0.w + c1.w + c2.w;
    }

    const int ccol = tid >> 2;            // 0..63: col for csRow accumulation
    const int ckq = (tid & 3) * 8;        // 8-k slice within BK=32
    float csAcc = 0.f;

    f32x4 acc[4][2] = {};

    stage(0, 0);
    __syncthreads();   // buf0 ready; csL visible
    int cur = 0;
    for (int k0 = 0; k0 < 1024; k0 += 32) {
        if (k0 + 32 < 1024) stage(cur ^ 1, k0 + 32);   // in flight under MFMA

        // csRow incremental: cs . Wo over this BK slice (hiB blocks only)
        if (hiB) {
            bf16x8 bv8 = *(const bf16x8*)&Bs[cur][ccol][ckq];
            float4 cl0 = *(const float4*)&csL[k0 + ckq];
            float4 cl1 = *(const float4*)&csL[k0 + ckq + 4];
            csAcc += cl0.x * bf2f((u16)bv8[0]) + cl0.y * bf2f((u16)bv8[1])
                   + cl0.z * bf2f((u16)bv8[2]) + cl0.w * bf2f((u16)bv8[3])
                   + cl1.x * bf2f((u16)bv8[4]) + cl1.y * bf2f((u16)bv8[5])
                   + cl1.z * bf2f((u16)bv8[6]) + cl1.w * bf2f((u16)bv8[7]);
        }

        bf16x8 bfr[2];
        #pragma unroll
        for (int nt = 0; nt < 2; ++nt)
            bfr[nt] = *(const bf16x8*)&Bs[cur][wn + nt * 16 + l16][quad * 8];
        #pragma unroll
        for (int mt = 0; mt < 4; ++mt) {
            bf16x8 aa = *(const bf16x8*)&Aa[cur][wm + mt * 16 + l16][quad * 8];
            bf16x8 ab = *(const bf16x8*)&Ab[cur][wm + mt * 16 + l16][quad * 8];
            bf16x8 ac = *(const bf16x8*)&Ac[cur][wm + mt * 16 + l16][quad * 8];
            #pragma unroll
            for (int nt = 0; nt < 2; ++nt) {
                acc[mt][nt] = __builtin_amdgcn_mfma_f32_16x16x32_bf16(
                    aa, bfr[nt], acc[mt][nt], 0, 0, 0);
                acc[mt][nt] = __builtin_amdgcn_mfma_f32_16x16x32_bf16(
                    ab, bfr[nt], acc[mt][nt], 0, 0, 0);
                acc[mt][nt] = __builtin_amdgcn_mfma_f32_16x16x32_bf16(
                    ac, bfr[nt], acc[mt][nt], 0, 0, 0);
            }
        }

        __syncthreads();   // frag reads done + next-tile loads landed
        cur ^= 1;
    }

    // reduce csRow partials (4 threads per col, adjacent lanes)
    if (hiB) {
        csAcc += __shfl_xor(csAcc, 1);
        csAcc += __shfl_xor(csAcc, 2);
        if ((tid & 3) == 0) csRowL[ccol] = csAcc;
    }
    __syncthreads();   // csRowL visible

    #pragma unroll
    for (int nt = 0; nt < 2; ++nt) {
        const int col = n0 + wn + nt * 16 + l16;
        const float bv = bias[col];
        const float cr = hiB ? csRowL[wn + nt * 16 + l16] : 0.f;
        #pragma unroll
        for (int mt = 0; mt < 4; ++mt) {
            #pragma unroll
            for (int r = 0; r < 4; ++r) {
                const int row = m0 + wm + mt * 16 + quad * 4 + r;
                const float o = acc[mt][nt][r];
                Y[(size_t)row * 1024 + col] = hiB ? (bv + cr - o) : (bv + o);
            }
        }
    }
}

// ---------------- fused MFMA attention, 128-row s-tile, 3-way t-split ---------
// Grid 768 = 16 heads x 16 s-tiles(128) x 3 t-splits (tiles {11,11,10}).
// K/V single-buffered (48 KB LDS -> 3 blocks/CU, 12 waves/CU): V staged at iter
// top (latency hides under QK^T+sigmoid), K for next iter staged after the mid
// barrier (hides under csum+PV). Two __syncthreads per iter. st==0 blocks fold
// their t-range's V1 column-sum into csP[spl].
__global__ __launch_bounds__(256, 3) void attn_mfma(
    const u16* __restrict__ Qb, const u16* __restrict__ Kb,
    const u16* __restrict__ VT, float* __restrict__ csP,
    u16* __restrict__ P0, u16* __restrict__ P1, u16* __restrict__ P2)
{
    __shared__ __attribute__((aligned(16))) u16 Ks[2][64][64];  // [b][t][dk]
    __shared__ __attribute__((aligned(16))) u16 Vs[2][64][64];  // [b][dk][t]
    __shared__ __attribute__((aligned(16))) u16 Ps[128][64];

    const int id = blockIdx.x;              // 0..767
    const int xcd = id & 7;                 // same-h blocks share an XCD's L2
    const int j = id >> 3;                  // 0..95
    const int h = xcd * 2 + (j & 1);
    const int r = j >> 1;                   // 0..47
    const int st = r & 15;
    const int spl = r >> 4;                 // 0..2
    const int s0 = st * 128;
    const int tstart = spl * 704;           // 11,11,10 tiles of 64
    const int ntile = (spl == 2) ? 10 : 11;
    u16* Pout = (spl == 0) ? P0 : (spl == 1) ? P1 : P2;

    const int tid = threadIdx.x;
    const int lane = tid & 63;
    const int wave = tid >> 6;
    const int quad = lane >> 4;
    const int l16 = lane & 15;
    const int sr8 = lane >> 3;              // row within 8-row staging chunk
    const int sc8 = lane & 7;               // physical 16B slot

    // async stage of one 64-t tile; LDS dest linear, source col pre-swizzled
    // (inverse of sw64: slot p of row r holds logical group (p - r) & 7).
    auto stageK = [&](int t0) {
        #pragma unroll
        for (int c = 0; c < 4; ++c) {
            const int kc = c * 4 + wave;           // chunk 0..15 (wave-uniform)
            const int bb = kc >> 3, row0 = (kc & 7) * 8;
            const int rr = row0 + sr8;
            const int cg = (sc8 - rr) & 7;
            async_cp16(Kb + (size_t)(bb * S_ + t0 + rr) * 1024 + h * 64 + cg * 8,
                       &Ks[bb][row0][0]);
        }
    };
    auto stageV = [&](int t0) {
        #pragma unroll
        for (int c = 0; c < 4; ++c) {
            const int kc = c * 4 + wave;
            const int bb = kc >> 3, row0 = (kc & 7) * 8;
            const int rr = row0 + sr8;
            const int cg = (sc8 - rr) & 7;
            async_cp16(VT + ((size_t)(bb * H_ + h) * 64 + rr) * 2048 + t0 + cg * 8,
                       &Vs[bb][row0][0]);
        }
    };

    // Q fragments: 32 s-rows per wave (2 s-groups of 16), both batches, k-halves
    bf16x8 qf[2][2][2];
    #pragma unroll
    for (int sg = 0; sg < 2; ++sg)
        #pragma unroll
        for (int b = 0; b < 2; ++b)
            #pragma unroll
            for (int ks = 0; ks < 2; ++ks)
                qf[sg][b][ks] = *(const bf16x8*)(Qb
                    + (size_t)(b * S_ + s0 + wave * 32 + sg * 16 + l16) * 1024
                    + h * 64 + ks * 32 + quad * 8);

    f32x4 O0[2][4] = {}, T1[2][4] = {};
    float cacc = 0.f;

    stageK(tstart);
    __syncthreads();                         // K(t_0) ready
    for (int i = 0; i < ntile; ++i) {
        const int t0 = tstart + i * 64;
        stageV(t0);                          // V in flight under QK^T+sigmoid

        // ---- QK^T: d = q0.k0 - q1.k1 (K b=1 sign pre-folded in proj3) ----
        f32x4 dacc[2][4] = {};
        __builtin_amdgcn_s_setprio(1);
        #pragma unroll
        for (int mt = 0; mt < 4; ++mt) {
            const int kr = mt * 16 + l16;
            #pragma unroll
            for (int ks = 0; ks < 2; ++ks) {
                bf16x8 k0f = *(const bf16x8*)&Ks[0][kr][sw64(kr, ks * 4 + quad)];
                bf16x8 k1f = *(const bf16x8*)&Ks[1][kr][sw64(kr, ks * 4 + quad)];
                #pragma unroll
                for (int sg = 0; sg < 2; ++sg) {
                    dacc[sg][mt] = __builtin_amdgcn_mfma_f32_16x16x32_bf16(
                        k0f, qf[sg][0][ks], dacc[sg][mt], 0, 0, 0);
                    dacc[sg][mt] = __builtin_amdgcn_mfma_f32_16x16x32_bf16(
                        k1f, qf[sg][1][ks], dacc[sg][mt], 0, 0, 0);
                }
            }
        }
        __builtin_amdgcn_s_setprio(0);

        // ---- batch-softmax == sigmoid(d/8); pack to Ps (wave-private rows) ----
        #pragma unroll
        for (int sg = 0; sg < 2; ++sg) {
            const int pr = wave * 32 + sg * 16 + l16;
            #pragma unroll
            for (int mt = 0; mt < 4; ++mt) {
                float p[4];
                #pragma unroll
                for (int rr = 0; rr < 4; ++rr) {
                    float e = __expf(dacc[sg][mt][rr] * -0.125f);
                    p[rr] = __builtin_amdgcn_rcpf(1.0f + e);
                }
                uint2 w;
                w.x = packtr(p[0], p[1]);
                w.y = packtr(p[2], p[3]);
                const int c8 = 2 * mt + (quad >> 1);
                *(uint2*)&Ps[pr][sw64(pr, c8) + (quad & 1) * 4] = w;
            }
        }

        __syncthreads();   // drains vmcnt(0): V tile ready; all K reads done

        if (i + 1 < ntile) stageK(t0 + 64);  // overwrite K safely; hides under PV

        // ---- V1 column-sum partial (only the 16x3 st==0 blocks) ----
        if (st == 0) {
            const int dk = tid >> 2, tp = tid & 3;
            bf16x8 vA = *(const bf16x8*)&Vs[1][dk][sw64(dk, tp * 2)];
            bf16x8 vB = *(const bf16x8*)&Vs[1][dk][sw64(dk, tp * 2 + 1)];
            #pragma unroll
            for (int jj = 0; jj < 8; ++jj)
                cacc += bf2f((u16)vA[jj]) + bf2f((u16)vB[jj]);
        }

        // ---- PV: V frags read once, reused across both s-groups ----
        bf16x8 pf[2][2];
        #pragma unroll
        for (int sg = 0; sg < 2; ++sg) {
            const int pr = wave * 32 + sg * 16 + l16;
            pf[sg][0] = *(const bf16x8*)&Ps[pr][sw64(pr, quad)];
            pf[sg][1] = *(const bf16x8*)&Ps[pr][sw64(pr, 4 + quad)];
        }
        __builtin_amdgcn_s_setprio(1);
        #pragma unroll
        for (int nt = 0; nt < 4; ++nt) {
            const int vr = nt * 16 + l16;
            bf16x8 v00 = *(const bf16x8*)&Vs[0][vr][sw64(vr, quad)];
            bf16x8 v01 = *(const bf16x8*)&Vs[0][vr][sw64(vr, 4 + quad)];
            bf16x8 v10 = *(const bf16x8*)&Vs[1][vr][sw64(vr, quad)];
            bf16x8 v11 = *(const bf16x8*)&Vs[1][vr][sw64(vr, 4 + quad)];
            #pragma unroll
            for (int sg = 0; sg < 2; ++sg) {
                O0[sg][nt] = __builtin_amdgcn_mfma_f32_16x16x32_bf16(pf[sg][0], v00, O0[sg][nt], 0, 0, 0);
                O0[sg][nt] = __builtin_amdgcn_mfma_f32_16x16x32_bf16(pf[sg][1], v01, O0[sg][nt], 0, 0, 0);
                T1[sg][nt] = __builtin_amdgcn_mfma_f32_16x16x32_bf16(pf[sg][0], v10, T1[sg][nt], 0, 0, 0);
                T1[sg][nt] = __builtin_amdgcn_mfma_f32_16x16x32_bf16(pf[sg][1], v11, T1[sg][nt], 0, 0, 0);
            }
        }
        __builtin_amdgcn_s_setprio(0);
        __syncthreads();   // all PV/csum reads done; K(next) landed
    }

    // ---- partial epilogue: b=0 stores O0, b=1 stores raw T1 (csum folded
    //      later in gemm_out: out1 = csum - (T1a + T1b + T1c)) ----
    #pragma unroll
    for (int sg = 0; sg < 2; ++sg)
        #pragma unroll
        for (int nt = 0; nt < 4; ++nt) {
            const int dk = nt * 16 + l16;
            #pragma unroll
            for (int rr = 0; rr < 4; ++rr) {
                const int s = s0 + wave * 32 + sg * 16 + quad * 4 + rr;
                Pout[(size_t)(0 * S_ + s) * 1024 + h * 64 + dk] = f2bf(O0[sg][nt][rr]);
                Pout[(size_t)(1 * S_ + s) * 1024 + h * 64 + dk] = f2bf(T1[sg][nt][rr]);
            }
        }

    if (st == 0) {
        cacc += __shfl_xor(cacc, 1);
        cacc += __shfl_xor(cacc, 2);
        if ((tid & 3) == 0)
            csP[spl * 1024 + h * 64 + (tid >> 2)] = cacc;
    }
}

extern "C" void kernel_launch(void* const* d_in, const int* in_sizes, int n_in,
                              void* d_out, int out_size, void* d_ws, size_t ws_size,
                              hipStream_t stream) {
    const float* q  = (const float*)d_in[0];
    const float* k  = (const float*)d_in[1];
    const float* v  = (const float*)d_in[2];
    const float* Wq = (const float*)d_in[3];
    const float* bq = (const float*)d_in[4];
    const float* Wk = (const float*)d_in[5];
    const float* bk = (const float*)d_in[6];
    const float* Wv = (const float*)d_in[7];
    const float* bv = (const float*)d_in[8];
    const float* Wo = (const float*)d_in[9];
    const float* bo = (const float*)d_in[10];

    char* ws = (char*)d_ws;
    const size_t MB = 1024 * 1024;
    u16* Xq  = (u16*)(ws);             // 8 MB, dead after proj3
    u16* Pa  = (u16*)(ws);             // attn split-0 partial (over Xq)
    u16* WqT = (u16*)(ws + 8  * MB);   // dead after proj3
    float* csP = (float*)(ws + 8 * MB);// 12 KB over WqT; attn writes, gemm reads
    u16* WkT = (u16*)(ws + 10 * MB);
    u16* WvT = (u16*)(ws + 12 * MB);
    u16* WoT = (u16*)(ws + 14 * MB);   // live till gemm_out
    u16* Qp  = (u16*)(ws + 16 * MB);
    u16* Kp  = (u16*)(ws + 24 * MB);
    u16* VTv = (u16*)(ws + 32 * MB);   // written directly by proj3 z==2
    u16* Xk  = (u16*)(ws + 40 * MB);   // dead after proj3
    u16* Pb  = (u16*)(ws + 40 * MB);   // attn split-1 partial (over Xk)
    u16* Xv  = (u16*)(ws + 48 * MB);   // dead after proj3
    u16* Pc  = (u16*)(ws + 48 * MB);   // attn split-2 partial (over Xv)

    dim3 blk(256);

    PrepArgs pr;
    pr.W[0] = Wq; pr.W[1] = Wk; pr.W[2] = Wv; pr.W[3] = Wo;
    pr.WT[0] = WqT; pr.WT[1] = WkT; pr.WT[2] = WvT; pr.WT[3] = WoT;
    pr.X[0] = q; pr.X[1] = k; pr.X[2] = v;
    pr.XB[0] = Xq; pr.XB[1] = Xk; pr.XB[2] = Xv;
    prep<<<dim3(1024 + 6144), blk, 0, stream>>>(pr);

    ProjArgs pa;
    pa.X[0] = Xq; pa.X[1] = Xk; pa.X[2] = Xv;
    pa.W[0] = WqT; pa.W[1] = WkT; pa.W[2] = WvT;
    pa.bias[0] = bq; pa.bias[1] = bk; pa.bias[2] = bv;
    pa.Y[0] = Qp; pa.Y[1] = Kp; pa.Y[2] = VTv;
    proj3<<<dim3(32, 8, 3), blk, 0, stream>>>(pa);

    attn_mfma<<<dim3(768), blk, 0, stream>>>(Qp, Kp, VTv, csP, Pa, Pb, Pc);
    gemm_out<<<dim3(32, 16), blk, 0, stream>>>(Pa, Pb, Pc, csP, WoT, bo, (float*)d_out);
}

// Round 7
// 235.537 us; speedup vs baseline: 1.0963x; 1.0963x over previous
//
#include <hip/hip_runtime.h>
#include <hip/hip_bf16.h>

#define B_ 2
#define S_ 2048
#define D_ 1024
#define H_ 16
#define DK_ 64
#define BS_ (B_ * S_)   // 4096

typedef unsigned int u32;
typedef unsigned short u16;
typedef __attribute__((ext_vector_type(8))) short bf16x8;
typedef __attribute__((ext_vector_type(4))) float f32x4;

typedef const __attribute__((address_space(1))) void glb_cv;
typedef __attribute__((address_space(3))) void lds_v;

__device__ __forceinline__ void async_cp16(const void* g, void* l) {
    __builtin_amdgcn_global_load_lds((glb_cv*)g, (lds_v*)l, 16, 0, 0);
}

__device__ __forceinline__ float bf2f(u16 v) {
    union { u32 u; float f; } c; c.u = ((u32)v) << 16; return c.f;
}
__device__ __forceinline__ u16 f2bf(float f) {   // RNE
    union { float f; u32 u; } c; c.f = f;
    u32 u = c.u;
    return (u16)((u + 0x7fffu + ((u >> 16) & 1u)) >> 16);
}
__device__ __forceinline__ u32 pack2(float a, float b) {
    return (u32)f2bf(a) | ((u32)f2bf(b) << 16);
}
// truncating pack (hot attn path only)
__device__ __forceinline__ u32 packtr(float lo, float hi) {
    union { float f; u32 u; } a, b; a.f = lo; b.f = hi;
    return __builtin_amdgcn_perm(b.u, a.u, 0x07060302u);
}
// LDS swizzle for attn tiles
__device__ __forceinline__ int sw64(int r, int c8) { return (((c8) + (r)) & 7) * 8; }

// ------------- fused prep: weight transposes + X f32->bf16 ------------------
// blocks [0,1024): weight transpose (z = id>>8); blocks [1024,7168): X convert.
struct PrepArgs {
    const float* W[4]; u16* WT[4];
    const float* X[3]; u16* XB[3];
};
__global__ __launch_bounds__(256) void prep(PrepArgs a)
{
    const int id = blockIdx.x;
    const int tid = threadIdx.x;
    if (id >= 1024) {   // ---- X convert: 2048 elems/block ----
        const int cid = id - 1024;
        const int z = cid >> 11;
        const size_t base = (size_t)(cid & 2047) * 2048 + tid * 8;
        const float* X = a.X[z];
        float4 x0 = *(const float4*)(X + base);
        float4 x1 = *(const float4*)(X + base + 4);
        uint4 o;
        o.x = pack2(x0.x, x0.y); o.y = pack2(x0.z, x0.w);
        o.z = pack2(x1.x, x1.y); o.w = pack2(x1.z, x1.w);
        *(uint4*)(a.XB[z] + base) = o;
        return;
    }
    __shared__ __attribute__((aligned(16))) u16 T[64][72];
    const int z = id >> 8;
    const int rem = id & 255;
    const float* W = a.W[z];
    u16* WT = a.WT[z];
    const int headMode = (z < 3) ? 1 : 0;
    const int k0 = (rem >> 4) * 64;
    const int n0 = (rem & 15) * 64;
    const int kr = tid >> 4;
    const int n4 = (tid & 15) * 4;
    #pragma unroll
    for (int pass = 0; pass < 4; ++pass) {
        int kk = k0 + pass * 16 + kr;
        const float* p = headMode
            ? (W + (size_t)((n0 + n4) >> 6) * (1024 * 64) + kk * 64 + ((n0 + n4) & 63))
            : (W + (size_t)kk * 1024 + n0 + n4);
        float4 v = *(const float4*)p;
        int krel = pass * 16 + kr;
        T[n4 + 0][krel] = f2bf(v.x);
        T[n4 + 1][krel] = f2bf(v.y);
        T[n4 + 2][krel] = f2bf(v.z);
        T[n4 + 3][krel] = f2bf(v.w);
    }
    __syncthreads();
    const int nr = tid >> 2;
    const int kq = (tid & 3) * 16;
    uint4 o0 = *(const uint4*)&T[nr][kq];
    uint4 o1 = *(const uint4*)&T[nr][kq + 8];
    u16* q = WT + (size_t)(n0 + nr) * 1024 + k0 + kq;
    *(uint4*)q = o0;
    *(uint4*)(q + 8) = o1;
}

// ---------------- fused projections, 64x128 tile, BK=64, 6 blocks/CU ---------
// Two-barrier m97 structure (proven): bar -> stage -> bar(vmcnt drain) -> MFMA.
// Smaller tile doubles resident blocks (grid 1536 = 6/CU, LDS 24 KB) so other
// blocks' MFMA hides each block's staging drain.
// z==1 negates rows >= 2048 (K batch-1 sign fold).
// z==2 writes DIRECTLY in transposed VT[b][h][dk][t] layout.
struct ProjArgs {
    const u16* X[3];
    const u16* W[3];
    const float* bias[3];
    u16* Y[3];
};
__global__ __launch_bounds__(256, 6) void proj3(ProjArgs pa)
{
    __shared__ __attribute__((aligned(16))) u16 As[2][64][32];
    __shared__ __attribute__((aligned(16))) u16 Bs[2][128][32];
    const int z = blockIdx.z;
    const u16* X = pa.X[z];
    const u16* WT = pa.W[z];
    const float* bias = pa.bias[z];
    u16* Y = pa.Y[z];
    const int neg = (z == 1);

    const int tid = threadIdx.x;
    const int lane = tid & 63;
    const int wave = tid >> 6;
    const int quad = lane >> 4;
    const int l16 = lane & 15;
    const int m0 = blockIdx.x * 64;
    const int n0 = blockIdx.y * 128;
    const int wm = (wave & 1) * 32, wn = (wave >> 1) * 64;

    f32x4 acc[2][4] = {};

    for (int k0 = 0; k0 < 1024; k0 += 64) {
        __syncthreads();   // prior iter's frag reads done
        #pragma unroll
        for (int ks = 0; ks < 2; ++ks) {
            {   // A tile: 64x32 = 256 chunks of 16B
                const int c = tid;
                const int row = c >> 2, cc = (c & 3) * 8;
                char* la = (char*)&As[ks][0][0] + (size_t)(c & ~63) * 16;
                async_cp16(X + (size_t)(m0 + row) * 1024 + k0 + ks * 32 + cc, la);
            }
            #pragma unroll
            for (int call = 0; call < 2; ++call) {   // B tile: 128x32 = 512 chunks
                const int c = tid + call * 256;
                const int row = c >> 2, cc = (c & 3) * 8;
                char* lb = (char*)&Bs[ks][0][0] + (size_t)(c & ~63) * 16;
                async_cp16(WT + (size_t)(n0 + row) * 1024 + k0 + ks * 32 + cc, lb);
            }
        }
        __syncthreads();   // drains vmcnt(0): LDS tiles ready

        #pragma unroll
        for (int ks = 0; ks < 2; ++ks) {
            bf16x8 af[2], bfr[4];
            #pragma unroll
            for (int mt = 0; mt < 2; ++mt)
                af[mt] = *(const bf16x8*)&As[ks][wm + mt * 16 + l16][quad * 8];
            #pragma unroll
            for (int nt = 0; nt < 4; ++nt)
                bfr[nt] = *(const bf16x8*)&Bs[ks][wn + nt * 16 + l16][quad * 8];
            #pragma unroll
            for (int mt = 0; mt < 2; ++mt)
                #pragma unroll
                for (int nt = 0; nt < 4; ++nt)
                    acc[mt][nt] = __builtin_amdgcn_mfma_f32_16x16x32_bf16(
                        af[mt], bfr[nt], acc[mt][nt], 0, 0, 0);
        }
    }

    if (z == 2) {
        // transposed V epilogue: VT[((b*16+h)*64+dk)*2048 + t]
        #pragma unroll
        for (int nt = 0; nt < 4; ++nt) {
            const int col = n0 + wn + nt * 16 + l16;
            const float bv = bias[col];
            u16* vrow = Y + ((size_t)(col >> 6) * 64 + (col & 63)) * 2048;
            #pragma unroll
            for (int mt = 0; mt < 2; ++mt) {
                const int row = m0 + wm + mt * 16 + quad * 4;
                const size_t boff = (size_t)(row >> 11) * (16 * 64 * 2048);
                const int t = row & 2047;
                uint2 w;
                w.x = pack2(acc[mt][nt][0] + bv, acc[mt][nt][1] + bv);
                w.y = pack2(acc[mt][nt][2] + bv, acc[mt][nt][3] + bv);
                *(uint2*)(vrow + boff + t) = w;
            }
        }
        return;
    }

    #pragma unroll
    for (int nt = 0; nt < 4; ++nt) {
        const int col = n0 + wn + nt * 16 + l16;
        const float bv = bias[col];
        #pragma unroll
        for (int mt = 0; mt < 2; ++mt) {
            #pragma unroll
            for (int r = 0; r < 4; ++r) {
                const int row = m0 + wm + mt * 16 + quad * 4 + r;
                float v = acc[mt][nt][r] + bv;
                if (neg && row >= 2048) v = -v;
                Y[(size_t)row * 1024 + col] = f2bf(v);
            }
        }
    }
}

// ---------------- output GEMM: d_out = (P0+P1+P2) . WoT^T + bo ---------------
// MFMA linearity: each bf16 partial fragment feeds MFMA directly into the SAME
// accumulator (no VALU combine, no re-round). hiB rows use
// out1 = cs.Wo - acc + bo, with csRow = cs.Wo accumulated incrementally from
// the staged Bs tile (8 FMA/thread/iter) and reduced at the end.
// Two-barrier structure (proven round-5). 128x64 tile, BK=32, grid 32x16.
__global__ __launch_bounds__(256) void gemm_out(
    const u16* __restrict__ P0, const u16* __restrict__ P1,
    const u16* __restrict__ P2, const float* __restrict__ csP,
    const u16* __restrict__ WT, const float* __restrict__ bias,
    float* __restrict__ Y)
{
    __shared__ __attribute__((aligned(16))) u16 Aa[128][32];
    __shared__ __attribute__((aligned(16))) u16 Ab[128][32];
    __shared__ __attribute__((aligned(16))) u16 Ac[128][32];
    __shared__ __attribute__((aligned(16))) u16 Bs[64][32];
    __shared__ __attribute__((aligned(16))) float csL[1024];
    __shared__ float csRowL[64];

    const int tid = threadIdx.x;
    const int lane = tid & 63;
    const int wave = tid >> 6;
    const int quad = lane >> 4;
    const int l16 = lane & 15;
    const int m0 = blockIdx.x * 128;
    const int n0 = blockIdx.y * 64;
    const int wm = (wave & 1) * 64, wn = (wave >> 1) * 32;
    const bool hiB = (m0 >= 2048);        // batch-1 rows (block-uniform)

    // one-time: combined csum vector into LDS (ordered by first loop barrier)
    if (hiB) {
        const int t4 = tid * 4;
        float4 c0 = *(const float4*)(csP + t4);
        float4 c1 = *(const float4*)(csP + 1024 + t4);
        float4 c2 = *(const float4*)(csP + 2048 + t4);
        csL[t4 + 0] = c0.x + c1.x + c2.x;
        csL[t4 + 1] = c0.y + c1.y + c2.y;
        csL[t4 + 2] = c0.z + c1.z + c2.z;
        csL[t4 + 3] = c0.w + c1.w + c2.w;
    }

    const int ccol = tid >> 2;            // 0..63: col for csRow accumulation
    const int ckq = (tid & 3) * 8;        // 8-k slice within BK=32
    float csAcc = 0.f;

    f32x4 acc[4][2] = {};

    for (int k0 = 0; k0 < 1024; k0 += 32) {
        __syncthreads();   // prev iter's frag reads done (+ csL write on iter0)
        #pragma unroll
        for (int call = 0; call < 2; ++call) {
            const int c = tid + call * 256;               // 512 chunks per A tile
            const int row = c >> 2, cc = (c & 3) * 8;
            char* la = (char*)&Aa[0][0] + (size_t)(c & ~63) * 16;
            async_cp16(P0 + (size_t)(m0 + row) * 1024 + k0 + cc, la);
            char* lb = (char*)&Ab[0][0] + (size_t)(c & ~63) * 16;
            async_cp16(P1 + (size_t)(m0 + row) * 1024 + k0 + cc, lb);
            char* lc = (char*)&Ac[0][0] + (size_t)(c & ~63) * 16;
            async_cp16(P2 + (size_t)(m0 + row) * 1024 + k0 + cc, lc);
        }
        {   // B: WoT tile, 256 chunks
            const int c = tid;
            const int row = c >> 2, cc = (c & 3) * 8;
            char* lb = (char*)&Bs[0][0] + (size_t)(c & ~63) * 16;
            async_cp16(WT + (size_t)(n0 + row) * 1024 + k0 + cc, lb);
        }
        __syncthreads();   // drains vmcnt(0): Aa/Ab/Ac/Bs ready

        // csRow incremental: cs . Wo over this BK slice (hiB blocks only)
        if (hiB) {
            bf16x8 bv8 = *(const bf16x8*)&Bs[ccol][ckq];
            float4 cl0 = *(const float4*)&csL[k0 + ckq];
            float4 cl1 = *(const float4*)&csL[k0 + ckq + 4];
            csAcc += cl0.x * bf2f((u16)bv8[0]) + cl0.y * bf2f((u16)bv8[1])
                   + cl0.z * bf2f((u16)bv8[2]) + cl0.w * bf2f((u16)bv8[3])
                   + cl1.x * bf2f((u16)bv8[4]) + cl1.y * bf2f((u16)bv8[5])
                   + cl1.z * bf2f((u16)bv8[6]) + cl1.w * bf2f((u16)bv8[7]);
        }

        bf16x8 bfr[2];
        #pragma unroll
        for (int nt = 0; nt < 2; ++nt)
            bfr[nt] = *(const bf16x8*)&Bs[wn + nt * 16 + l16][quad * 8];
        #pragma unroll
        for (int mt = 0; mt < 4; ++mt) {
            bf16x8 aa = *(const bf16x8*)&Aa[wm + mt * 16 + l16][quad * 8];
            bf16x8 ab = *(const bf16x8*)&Ab[wm + mt * 16 + l16][quad * 8];
            bf16x8 ac = *(const bf16x8*)&Ac[wm + mt * 16 + l16][quad * 8];
            #pragma unroll
            for (int nt = 0; nt < 2; ++nt) {
                acc[mt][nt] = __builtin_amdgcn_mfma_f32_16x16x32_bf16(
                    aa, bfr[nt], acc[mt][nt], 0, 0, 0);
                acc[mt][nt] = __builtin_amdgcn_mfma_f32_16x16x32_bf16(
                    ab, bfr[nt], acc[mt][nt], 0, 0, 0);
                acc[mt][nt] = __builtin_amdgcn_mfma_f32_16x16x32_bf16(
                    ac, bfr[nt], acc[mt][nt], 0, 0, 0);
            }
        }
    }

    // reduce csRow partials (4 threads per col, adjacent lanes)
    if (hiB) {
        csAcc += __shfl_xor(csAcc, 1);
        csAcc += __shfl_xor(csAcc, 2);
        if ((tid & 3) == 0) csRowL[ccol] = csAcc;
    }
    __syncthreads();   // csRowL visible

    #pragma unroll
    for (int nt = 0; nt < 2; ++nt) {
        const int col = n0 + wn + nt * 16 + l16;
        const float bv = bias[col];
        const float cr = hiB ? csRowL[wn + nt * 16 + l16] : 0.f;
        #pragma unroll
        for (int mt = 0; mt < 4; ++mt) {
            #pragma unroll
            for (int r = 0; r < 4; ++r) {
                const int row = m0 + wm + mt * 16 + quad * 4 + r;
                const float o = acc[mt][nt][r];
                Y[(size_t)row * 1024 + col] = hiB ? (bv + cr - o) : (bv + o);
            }
        }
    }
}

// ---------------- fused MFMA attention, 128-row s-tile, 3-way t-split ---------
// Grid 768 = 16 heads x 16 s-tiles(128) x 3 t-splits (tiles {11,11,10}).
// K/V single-buffered (48 KB LDS -> 3 blocks/CU, 12 waves/CU): V staged at iter
// top (latency hides under QK^T+sigmoid), K for next iter staged after the mid
// barrier (hides under csum+PV). Two __syncthreads per iter. st==0 blocks fold
// their t-range's V1 column-sum into csP[spl].
__global__ __launch_bounds__(256, 3) void attn_mfma(
    const u16* __restrict__ Qb, const u16* __restrict__ Kb,
    const u16* __restrict__ VT, float* __restrict__ csP,
    u16* __restrict__ P0, u16* __restrict__ P1, u16* __restrict__ P2)
{
    __shared__ __attribute__((aligned(16))) u16 Ks[2][64][64];  // [b][t][dk]
    __shared__ __attribute__((aligned(16))) u16 Vs[2][64][64];  // [b][dk][t]
    __shared__ __attribute__((aligned(16))) u16 Ps[128][64];

    const int id = blockIdx.x;              // 0..767
    const int xcd = id & 7;                 // same-h blocks share an XCD's L2
    const int j = id >> 3;                  // 0..95
    const int h = xcd * 2 + (j & 1);
    const int r = j >> 1;                   // 0..47
    const int st = r & 15;
    const int spl = r >> 4;                 // 0..2
    const int s0 = st * 128;
    const int tstart = spl * 704;           // 11,11,10 tiles of 64
    const int ntile = (spl == 2) ? 10 : 11;
    u16* Pout = (spl == 0) ? P0 : (spl == 1) ? P1 : P2;

    const int tid = threadIdx.x;
    const int lane = tid & 63;
    const int wave = tid >> 6;
    const int quad = lane >> 4;
    const int l16 = lane & 15;
    const int sr8 = lane >> 3;              // row within 8-row staging chunk
    const int sc8 = lane & 7;               // physical 16B slot

    // async stage of one 64-t tile; LDS dest linear, source col pre-swizzled
    // (inverse of sw64: slot p of row r holds logical group (p - r) & 7).
    auto stageK = [&](int t0) {
        #pragma unroll
        for (int c = 0; c < 4; ++c) {
            const int kc = c * 4 + wave;           // chunk 0..15 (wave-uniform)
            const int bb = kc >> 3, row0 = (kc & 7) * 8;
            const int rr = row0 + sr8;
            const int cg = (sc8 - rr) & 7;
            async_cp16(Kb + (size_t)(bb * S_ + t0 + rr) * 1024 + h * 64 + cg * 8,
                       &Ks[bb][row0][0]);
        }
    };
    auto stageV = [&](int t0) {
        #pragma unroll
        for (int c = 0; c < 4; ++c) {
            const int kc = c * 4 + wave;
            const int bb = kc >> 3, row0 = (kc & 7) * 8;
            const int rr = row0 + sr8;
            const int cg = (sc8 - rr) & 7;
            async_cp16(VT + ((size_t)(bb * H_ + h) * 64 + rr) * 2048 + t0 + cg * 8,
                       &Vs[bb][row0][0]);
        }
    };

    // Q fragments: 32 s-rows per wave (2 s-groups of 16), both batches, k-halves
    bf16x8 qf[2][2][2];
    #pragma unroll
    for (int sg = 0; sg < 2; ++sg)
        #pragma unroll
        for (int b = 0; b < 2; ++b)
            #pragma unroll
            for (int ks = 0; ks < 2; ++ks)
                qf[sg][b][ks] = *(const bf16x8*)(Qb
                    + (size_t)(b * S_ + s0 + wave * 32 + sg * 16 + l16) * 1024
                    + h * 64 + ks * 32 + quad * 8);

    f32x4 O0[2][4] = {}, T1[2][4] = {};
    float cacc = 0.f;

    stageK(tstart);
    __syncthreads();                         // K(t_0) ready
    for (int i = 0; i < ntile; ++i) {
        const int t0 = tstart + i * 64;
        stageV(t0);                          // V in flight under QK^T+sigmoid

        // ---- QK^T: d = q0.k0 - q1.k1 (K b=1 sign pre-folded in proj3) ----
        f32x4 dacc[2][4] = {};
        __builtin_amdgcn_s_setprio(1);
        #pragma unroll
        for (int mt = 0; mt < 4; ++mt) {
            const int kr = mt * 16 + l16;
            #pragma unroll
            for (int ks = 0; ks < 2; ++ks) {
                bf16x8 k0f = *(const bf16x8*)&Ks[0][kr][sw64(kr, ks * 4 + quad)];
                bf16x8 k1f = *(const bf16x8*)&Ks[1][kr][sw64(kr, ks * 4 + quad)];
                #pragma unroll
                for (int sg = 0; sg < 2; ++sg) {
                    dacc[sg][mt] = __builtin_amdgcn_mfma_f32_16x16x32_bf16(
                        k0f, qf[sg][0][ks], dacc[sg][mt], 0, 0, 0);
                    dacc[sg][mt] = __builtin_amdgcn_mfma_f32_16x16x32_bf16(
                        k1f, qf[sg][1][ks], dacc[sg][mt], 0, 0, 0);
                }
            }
        }
        __builtin_amdgcn_s_setprio(0);

        // ---- batch-softmax == sigmoid(d/8); pack to Ps (wave-private rows) ----
        #pragma unroll
        for (int sg = 0; sg < 2; ++sg) {
            const int pr = wave * 32 + sg * 16 + l16;
            #pragma unroll
            for (int mt = 0; mt < 4; ++mt) {
                float p[4];
                #pragma unroll
                for (int rr = 0; rr < 4; ++rr) {
                    float e = __expf(dacc[sg][mt][rr] * -0.125f);
                    p[rr] = __builtin_amdgcn_rcpf(1.0f + e);
                }
                uint2 w;
                w.x = packtr(p[0], p[1]);
                w.y = packtr(p[2], p[3]);
                const int c8 = 2 * mt + (quad >> 1);
                *(uint2*)&Ps[pr][sw64(pr, c8) + (quad & 1) * 4] = w;
            }
        }

        __syncthreads();   // drains vmcnt(0): V tile ready; all K reads done

        if (i + 1 < ntile) stageK(t0 + 64);  // overwrite K safely; hides under PV

        // ---- V1 column-sum partial (only the 16x3 st==0 blocks) ----
        if (st == 0) {
            const int dk = tid >> 2, tp = tid & 3;
            bf16x8 vA = *(const bf16x8*)&Vs[1][dk][sw64(dk, tp * 2)];
            bf16x8 vB = *(const bf16x8*)&Vs[1][dk][sw64(dk, tp * 2 + 1)];
            #pragma unroll
            for (int jj = 0; jj < 8; ++jj)
                cacc += bf2f((u16)vA[jj]) + bf2f((u16)vB[jj]);
        }

        // ---- PV: V frags read once, reused across both s-groups ----
        bf16x8 pf[2][2];
        #pragma unroll
        for (int sg = 0; sg < 2; ++sg) {
            const int pr = wave * 32 + sg * 16 + l16;
            pf[sg][0] = *(const bf16x8*)&Ps[pr][sw64(pr, quad)];
            pf[sg][1] = *(const bf16x8*)&Ps[pr][sw64(pr, 4 + quad)];
        }
        __builtin_amdgcn_s_setprio(1);
        #pragma unroll
        for (int nt = 0; nt < 4; ++nt) {
            const int vr = nt * 16 + l16;
            bf16x8 v00 = *(const bf16x8*)&Vs[0][vr][sw64(vr, quad)];
            bf16x8 v01 = *(const bf16x8*)&Vs[0][vr][sw64(vr, 4 + quad)];
            bf16x8 v10 = *(const bf16x8*)&Vs[1][vr][sw64(vr, quad)];
            bf16x8 v11 = *(const bf16x8*)&Vs[1][vr][sw64(vr, 4 + quad)];
            #pragma unroll
            for (int sg = 0; sg < 2; ++sg) {
                O0[sg][nt] = __builtin_amdgcn_mfma_f32_16x16x32_bf16(pf[sg][0], v00, O0[sg][nt], 0, 0, 0);
                O0[sg][nt] = __builtin_amdgcn_mfma_f32_16x16x32_bf16(pf[sg][1], v01, O0[sg][nt], 0, 0, 0);
                T1[sg][nt] = __builtin_amdgcn_mfma_f32_16x16x32_bf16(pf[sg][0], v10, T1[sg][nt], 0, 0, 0);
                T1[sg][nt] = __builtin_amdgcn_mfma_f32_16x16x32_bf16(pf[sg][1], v11, T1[sg][nt], 0, 0, 0);
            }
        }
        __builtin_amdgcn_s_setprio(0);
        __syncthreads();   // all PV/csum reads done; K(next) landed
    }

    // ---- partial epilogue: b=0 stores O0, b=1 stores raw T1 (csum folded
    //      later in gemm_out: out1 = csum - (T1a + T1b + T1c)) ----
    #pragma unroll
    for (int sg = 0; sg < 2; ++sg)
        #pragma unroll
        for (int nt = 0; nt < 4; ++nt) {
            const int dk = nt * 16 + l16;
            #pragma unroll
            for (int rr = 0; rr < 4; ++rr) {
                const int s = s0 + wave * 32 + sg * 16 + quad * 4 + rr;
                Pout[(size_t)(0 * S_ + s) * 1024 + h * 64 + dk] = f2bf(O0[sg][nt][rr]);
                Pout[(size_t)(1 * S_ + s) * 1024 + h * 64 + dk] = f2bf(T1[sg][nt][rr]);
            }
        }

    if (st == 0) {
        cacc += __shfl_xor(cacc, 1);
        cacc += __shfl_xor(cacc, 2);
        if ((tid & 3) == 0)
            csP[spl * 1024 + h * 64 + (tid >> 2)] = cacc;
    }
}

extern "C" void kernel_launch(void* const* d_in, const int* in_sizes, int n_in,
                              void* d_out, int out_size, void* d_ws, size_t ws_size,
                              hipStream_t stream) {
    const float* q  = (const float*)d_in[0];
    const float* k  = (const float*)d_in[1];
    const float* v  = (const float*)d_in[2];
    const float* Wq = (const float*)d_in[3];
    const float* bq = (const float*)d_in[4];
    const float* Wk = (const float*)d_in[5];
    const float* bk = (const float*)d_in[6];
    const float* Wv = (const float*)d_in[7];
    const float* bv = (const float*)d_in[8];
    const float* Wo = (const float*)d_in[9];
    const float* bo = (const float*)d_in[10];

    char* ws = (char*)d_ws;
    const size_t MB = 1024 * 1024;
    u16* Xq  = (u16*)(ws);             // 8 MB, dead after proj3
    u16* Pa  = (u16*)(ws);             // attn split-0 partial (over Xq)
    u16* WqT = (u16*)(ws + 8  * MB);   // dead after proj3
    float* csP = (float*)(ws + 8 * MB);// 12 KB over WqT; attn writes, gemm reads
    u16* WkT = (u16*)(ws + 10 * MB);
    u16* WvT = (u16*)(ws + 12 * MB);
    u16* WoT = (u16*)(ws + 14 * MB);   // live till gemm_out
    u16* Qp  = (u16*)(ws + 16 * MB);
    u16* Kp  = (u16*)(ws + 24 * MB);
    u16* VTv = (u16*)(ws + 32 * MB);   // written directly by proj3 z==2
    u16* Xk  = (u16*)(ws + 40 * MB);   // dead after proj3
    u16* Pb  = (u16*)(ws + 40 * MB);   // attn split-1 partial (over Xk)
    u16* Xv  = (u16*)(ws + 48 * MB);   // dead after proj3
    u16* Pc  = (u16*)(ws + 48 * MB);   // attn split-2 partial (over Xv)

    dim3 blk(256);

    PrepArgs pr;
    pr.W[0] = Wq; pr.W[1] = Wk; pr.W[2] = Wv; pr.W[3] = Wo;
    pr.WT[0] = WqT; pr.WT[1] = WkT; pr.WT[2] = WvT; pr.WT[3] = WoT;
    pr.X[0] = q; pr.X[1] = k; pr.X[2] = v;
    pr.XB[0] = Xq; pr.XB[1] = Xk; pr.XB[2] = Xv;
    prep<<<dim3(1024 + 6144), blk, 0, stream>>>(pr);

    ProjArgs pa;
    pa.X[0] = Xq; pa.X[1] = Xk; pa.X[2] = Xv;
    pa.W[0] = WqT; pa.W[1] = WkT; pa.W[2] = WvT;
    pa.bias[0] = bq; pa.bias[1] = bk; pa.bias[2] = bv;
    pa.Y[0] = Qp; pa.Y[1] = Kp; pa.Y[2] = VTv;
    proj3<<<dim3(64, 8, 3), blk, 0, stream>>>(pa);

    attn_mfma<<<dim3(768), blk, 0, stream>>>(Qp, Kp, VTv, csP, Pa, Pb, Pc);
    gemm_out<<<dim3(32, 16), blk, 0, stream>>>(Pa, Pb, Pc, csP, WoT, bo, (float*)d_out);
}